// Round 5
// baseline (106.662 us; speedup 1.0000x reference)
//
#include <hip/hip_runtime.h>
#include <hip/hip_bf16.h>
#include <math.h>

// Problem constants
#define NB   16      // batch
#define NIN  512
#define NN   2048
#define KN   28672   // K*N
#define KN2  14336   // KN/2

// ---------------------------------------------------------------------------
// k12: fused input-GEMM + LIF. One block = 64 neurons (n), all 16 batches.
// Phase 1: thread (n_l, s) accumulates k-slice [s*128, s*128+128) in f64.
// Phase 2: fixed-order reduce over s (k-ascending == previous versions,
// bit-identical), LIF update, write z/v, assemble zmask nibbles in LDS.
// No atomics, no global partials, no memset.
__global__ __launch_bounds__(256) void k12_fused(const float* __restrict__ inputs,
                                                 const float* __restrict__ W,
                                                 const float* __restrict__ old_v,
                                                 const float* __restrict__ old_spike,
                                                 const int* __restrict__ tt_p,
                                                 float* __restrict__ out,   // z @0, v @32768
                                                 unsigned int* __restrict__ zmask) {
    __shared__ double pacc[4][16][64];        // 32 KB
    __shared__ unsigned char zbits[4][64];
    const int t   = threadIdx.x;
    const int n_l = t & 63, s = t >> 6;
    const int n   = blockIdx.x * 64 + n_l;
    const int k0  = s * 128;

    double acc[16];
    #pragma unroll
    for (int b = 0; b < 16; ++b) acc[b] = 0.0;
    #pragma unroll 2
    for (int kk = 0; kk < 128; ++kk) {
        double w = (double)W[(size_t)(k0 + kk) * NN + n];   // coalesced 256B/wave
        #pragma unroll
        for (int b = 0; b < 16; ++b)                        // uniform scalar loads
            acc[b] += w * (double)inputs[b * NIN + k0 + kk];
    }
    #pragma unroll
    for (int b = 0; b < 16; ++b) pacc[s][b][n_l] = acc[b];
    __syncthreads();

    // Phase 2: thread handles 4 (b,n) pairs: b = bq*4+j, same n_l.
    const int bq = s;                          // reuse t>>6 as batch quad
    double tt   = (double)tt_p[0];
    double bias = 0.5 * sin(2.0 * 3.14159265358979323846 * 4.0 * (0.001 * tt));
    const double d = 0.9512294245007140;       // exp(-1/20)
    unsigned int nib = 0;
    #pragma unroll
    for (int j = 0; j < 4; ++j) {
        int b = bq * 4 + j;
        double ssum = pacc[0][b][n_l] + pacc[1][b][n_l]
                    + pacc[2][b][n_l] + pacc[3][b][n_l];   // k-ascending order
        int gid = b * NN + n;
        double nv = d * (double)old_v[gid] + (1.0 - d) * (ssum + bias)
                    - 0.03 * (double)old_spike[gid];
        bool z = nv > 0.03;                    // v_scaled > 0  <=>  nv > THR
        out[gid]         = z ? 1.0f : 0.0f;
        out[32768 + gid] = (float)nv;
        nib |= (z ? 1u : 0u) << j;
    }
    zbits[bq][n_l] = (unsigned char)nib;
    __syncthreads();
    if (t < 64) {
        unsigned int m = (unsigned int)zbits[0][t]
                       | ((unsigned int)zbits[1][t] << 4)
                       | ((unsigned int)zbits[2][t] << 8)
                       | ((unsigned int)zbits[3][t] << 12);
        zmask[blockIdx.x * 64 + t] = m;
    }
}

// ---------------------------------------------------------------------------
// k3: streamed masked row-sum of B (= new_z @ B).
// float2 per thread (VGPR < 64: 32 acc split-scalar + 16 in-flight),
// branchless selector-FMA with wave-uniform mask, UN=8 batched loads.
// Grid 112 x 16 = 1792 blocks of 128 thr -> exactly 7 blocks/CU (balanced).
#define UN 8
__global__ __launch_bounds__(128) void k3_stream(const float2* __restrict__ B2,
                                                 const unsigned int* __restrict__ zmask,
                                                 float2* __restrict__ ZBp2,
                                                 int nper) {
    __shared__ unsigned int smask[512];
    const int t    = threadIdx.x;
    const int col2 = blockIdx.x * 128 + t;       // [0, 14336)
    const int n0   = blockIdx.y * nper;
    for (int j = t; j < nper; j += 128) smask[j] = zmask[n0 + j];
    __syncthreads();

    float accx[16], accy[16];
    #pragma unroll
    for (int b = 0; b < 16; ++b) { accx[b] = 0.f; accy[b] = 0.f; }

    const float2* p = B2 + (size_t)n0 * KN2 + col2;
    for (int j = 0; j < nper; j += UN) {
        float2 v[UN];
        #pragma unroll
        for (int u = 0; u < UN; ++u)             // batched: 8 x 8B in flight
            v[u] = p[(size_t)(j + u) * KN2];
        #pragma unroll
        for (int u = 0; u < UN; ++u) {
            unsigned int m = (unsigned int)
                __builtin_amdgcn_readfirstlane((int)smask[j + u]);
            #pragma unroll
            for (int b = 0; b < 16; ++b) {
                float s = (m & (1u << b)) ? 1.0f : 0.0f;   // SGPR cselect
                accx[b] = fmaf(s, v[u].x, accx[b]);        // exact: +v or +0
                accy[b] = fmaf(s, v[u].y, accy[b]);
            }
        }
    }
    #pragma unroll
    for (int b = 0; b < 16; ++b) {
        float2 o; o.x = accx[b]; o.y = accy[b];
        ZBp2[(size_t)(blockIdx.y * 16 + b) * KN2 + col2] = o;
    }
}

// ---------------------------------------------------------------------------
// k4: gather the 2048 indexed columns, reduce NC chunk-partials (fixed order).
// 256 blocks x 128 thr = 1 block/CU.
__global__ __launch_bounds__(128) void k4_gather(const float* __restrict__ ZBp,
                                                 const int* __restrict__ ridx,
                                                 float* __restrict__ out_z2,
                                                 int NC) {
    int gid = blockIdx.x * 128 + threadIdx.x;   // [0, 32768)
    int b = gid >> 11, i = gid & (NN - 1);
    int r = ridx[i];
    float acc = 0.f;
    #pragma unroll 4
    for (int c = 0; c < NC; ++c)                // independent loads, pipelined
        acc += ZBp[(size_t)(c * 16 + b) * KN + r];
    out_z2[gid] = acc;
}

// ---------------------------------------------------------------------------
extern "C" void kernel_launch(void* const* d_in, const int* in_sizes, int n_in,
                              void* d_out, int out_size, void* d_ws, size_t ws_size,
                              hipStream_t stream) {
    const float* inputs    = (const float*)d_in[0];
    const float* old_v     = (const float*)d_in[1];
    const float* old_spike = (const float*)d_in[2];
    const float* W         = (const float*)d_in[3];
    const float* Bw        = (const float*)d_in[4];
    const int*   ridx      = (const int*)d_in[5];
    const int*   tt        = (const int*)d_in[6];
    float* out = (float*)d_out;

    // ws layout: [0,64KB) zmask | ZB partials
    char* ws = (char*)d_ws;
    unsigned int* zmask = (unsigned int*)ws;
    float*        ZBp   = (float*)(ws + (64u << 10));

    size_t fixed = (64u << 10);
    size_t avail = ws_size > fixed ? ws_size - fixed : 0;
    int NC = 16;                                   // n-chunks for k3 (pow2)
    while (NC > 2 && (size_t)NC * 16 * KN * sizeof(float) > avail) NC >>= 1;
    int nper = NN / NC;                            // multiple of UN

    k12_fused<<<32, 256, 0, stream>>>(inputs, W, old_v, old_spike, tt, out, zmask);
    k3_stream<<<dim3(112, NC), 128, 0, stream>>>((const float2*)Bw, zmask,
                                                 (float2*)ZBp, nper);
    k4_gather<<<256, 128, 0, stream>>>(ZBp, ridx, out + 65536, NC);
}

// Round 6
// 78.829 us; speedup vs baseline: 1.3531x; 1.3531x over previous
//
#include <hip/hip_runtime.h>
#include <hip/hip_bf16.h>
#include <math.h>

// Problem constants
#define NB   16      // batch
#define NIN  512
#define NN   2048
#define KN   28672   // K*N
#define KN2  14336   // KN/2

// ---------------------------------------------------------------------------
// k1: partial GEMM i_in = inputs @ W, f64 accumulation, deterministic order.
// part[ks][b][n], ks in [0,16) covering k = ks*32 .. ks*32+31.
// grid (32 n-chunks, 16 ks), block = 64 threads (one wave, 64 n's).
// by==0 blocks also clear zmask (read only by k2, after k1 completes).
__global__ __launch_bounds__(64) void k1_gemm(const float* __restrict__ inputs,
                                              const float* __restrict__ W,
                                              double* __restrict__ part,
                                              unsigned int* __restrict__ zmask) {
    const int n  = blockIdx.x * 64 + threadIdx.x;
    const int ks = blockIdx.y;
    if (ks == 0) zmask[n] = 0u;                 // fused clear, no extra dispatch
    const int k0 = ks * 32;
    double acc[16];
    #pragma unroll
    for (int b = 0; b < 16; ++b) acc[b] = 0.0;
    #pragma unroll 8
    for (int kk = 0; kk < 32; ++kk) {           // 8 W-loads batched in flight
        double w = (double)W[(size_t)(k0 + kk) * NN + n];   // coalesced 256B/wave
        #pragma unroll
        for (int b = 0; b < 16; ++b)                        // uniform scalar loads
            acc[b] += w * (double)inputs[b * NIN + k0 + kk];
    }
    #pragma unroll
    for (int b = 0; b < 16; ++b)
        part[(size_t)(ks * 16 + b) * NN + n] = acc[b];
}

// ---------------------------------------------------------------------------
// k2: deterministic reduce of 16 partials + LIF update. Writes new_z, new_v,
// and per-neuron 16-bit spike mask (atomicOr = order-independent).
__global__ __launch_bounds__(256) void k2_point(const double* __restrict__ part,
                                                const float* __restrict__ old_v,
                                                const float* __restrict__ old_spike,
                                                const int* __restrict__ tt_p,
                                                float* __restrict__ out,      // z @0, v @32768
                                                unsigned int* __restrict__ zmask) {
    int gid = blockIdx.x * 256 + threadIdx.x;   // [0, 32768)
    int b = gid >> 11, n = gid & (NN - 1);
    double s = 0.0;
    #pragma unroll
    for (int ks = 0; ks < 16; ++ks)             // fixed order -> deterministic
        s += part[(size_t)(ks * 16 + b) * NN + n];
    double tt   = (double)tt_p[0];
    double bias = 0.5 * sin(2.0 * 3.14159265358979323846 * 4.0 * (0.001 * tt));
    double d    = 0.9512294245007140;           // exp(-1/20)
    double i_in = s + bias;
    double nv   = d * (double)old_v[gid] + (1.0 - d) * i_in
                  - 0.03 * (double)old_spike[gid];
    bool z = nv > 0.03;                          // v_scaled > 0  <=>  nv > THR
    out[gid]           = z ? 1.0f : 0.0f;
    out[32768 + gid]   = (float)nv;
    if (z) atomicOr(&zmask[n], 1u << b);
}

// ---------------------------------------------------------------------------
// k3: streamed masked row-sum of B (= new_z @ B).
// float2 per thread (VGPR < 64: 32 acc split-scalar + 16 in-flight),
// branchless selector-FMA with wave-uniform mask, UN=8 batched loads.
// Grid 112 x 16 = 1792 blocks of 128 thr -> exactly 7 blocks/CU (balanced).
#define UN 8
__global__ __launch_bounds__(128) void k3_stream(const float2* __restrict__ B2,
                                                 const unsigned int* __restrict__ zmask,
                                                 float2* __restrict__ ZBp2,
                                                 int nper) {
    __shared__ unsigned int smask[512];
    const int t    = threadIdx.x;
    const int col2 = blockIdx.x * 128 + t;       // [0, 14336)
    const int n0   = blockIdx.y * nper;
    for (int j = t; j < nper; j += 128) smask[j] = zmask[n0 + j];
    __syncthreads();

    float accx[16], accy[16];
    #pragma unroll
    for (int b = 0; b < 16; ++b) { accx[b] = 0.f; accy[b] = 0.f; }

    const float2* p = B2 + (size_t)n0 * KN2 + col2;
    for (int j = 0; j < nper; j += UN) {
        float2 v[UN];
        #pragma unroll
        for (int u = 0; u < UN; ++u)             // batched: 8 x 8B in flight
            v[u] = p[(size_t)(j + u) * KN2];
        #pragma unroll
        for (int u = 0; u < UN; ++u) {
            unsigned int m = (unsigned int)
                __builtin_amdgcn_readfirstlane((int)smask[j + u]);
            #pragma unroll
            for (int b = 0; b < 16; ++b) {
                float s = (m & (1u << b)) ? 1.0f : 0.0f;   // SGPR cselect
                accx[b] = fmaf(s, v[u].x, accx[b]);        // exact: +v or +0
                accy[b] = fmaf(s, v[u].y, accy[b]);
            }
        }
    }
    #pragma unroll
    for (int b = 0; b < 16; ++b) {
        float2 o; o.x = accx[b]; o.y = accy[b];
        ZBp2[(size_t)(blockIdx.y * 16 + b) * KN2 + col2] = o;
    }
}

// ---------------------------------------------------------------------------
// k4: gather the 2048 indexed columns, reduce NC chunk-partials (fixed order).
// 256 blocks x 128 thr = 1 block/CU.
__global__ __launch_bounds__(128) void k4_gather(const float* __restrict__ ZBp,
                                                 const int* __restrict__ ridx,
                                                 float* __restrict__ out_z2,
                                                 int NC) {
    int gid = blockIdx.x * 128 + threadIdx.x;   // [0, 32768)
    int b = gid >> 11, i = gid & (NN - 1);
    int r = ridx[i];
    float acc = 0.f;
    #pragma unroll 4
    for (int c = 0; c < NC; ++c)                // independent loads, pipelined
        acc += ZBp[(size_t)(c * 16 + b) * KN + r];
    out_z2[gid] = acc;
}

// ---------------------------------------------------------------------------
extern "C" void kernel_launch(void* const* d_in, const int* in_sizes, int n_in,
                              void* d_out, int out_size, void* d_ws, size_t ws_size,
                              hipStream_t stream) {
    const float* inputs    = (const float*)d_in[0];
    const float* old_v     = (const float*)d_in[1];
    const float* old_spike = (const float*)d_in[2];
    const float* W         = (const float*)d_in[3];
    const float* Bw        = (const float*)d_in[4];
    const int*   ridx      = (const int*)d_in[5];
    const int*   tt        = (const int*)d_in[6];
    float* out = (float*)d_out;

    // ws layout: [0,4MB) f64 i_in partials | [4MB,+64KB) zmask | ZB partials
    char* ws = (char*)d_ws;
    double*       part  = (double*)ws;
    unsigned int* zmask = (unsigned int*)(ws + (4u << 20));
    float*        ZBp   = (float*)(ws + (4u << 20) + (64u << 10));

    size_t fixed = (4u << 20) + (64u << 10);
    size_t avail = ws_size > fixed ? ws_size - fixed : 0;
    int NC = 16;                                   // n-chunks for k3 (pow2)
    while (NC > 2 && (size_t)NC * 16 * KN * sizeof(float) > avail) NC >>= 1;
    int nper = NN / NC;                            // multiple of UN

    k1_gemm <<<dim3(32, 16), 64, 0, stream>>>(inputs, W, part, zmask);
    k2_point<<<128, 256, 0, stream>>>(part, old_v, old_spike, tt, out, zmask);
    k3_stream<<<dim3(112, NC), 128, 0, stream>>>((const float2*)Bw, zmask,
                                                 (float2*)ZBp, nper);
    k4_gather<<<256, 128, 0, stream>>>(ZBp, ridx, out + 65536, NC);
}

// Round 7
// 73.753 us; speedup vs baseline: 1.4462x; 1.0688x over previous
//
#include <hip/hip_runtime.h>
#include <hip/hip_bf16.h>
#include <math.h>

// Problem constants
#define NB   16      // batch
#define NIN  512
#define NN   2048
#define KN   28672   // K*N
#define KN2  14336   // KN/2
#define INVNONE 0x7fffffff

// ---------------------------------------------------------------------------
// k1: partial GEMM i_in = inputs @ W, f64 accumulation, deterministic order.
// part[ks][b][n], ks in [0,16) covering k = ks*32 .. ks*32+31.
// grid (32 n-chunks, 16 ks), block = 64 threads (one wave, 64 n's).
// Also clears zmask (ks==0 blocks) and inits inv[] (all blocks, 1 elem/thread).
__global__ __launch_bounds__(64) void k1_gemm(const float* __restrict__ inputs,
                                              const float* __restrict__ W,
                                              double* __restrict__ part,
                                              unsigned int* __restrict__ zmask,
                                              int* __restrict__ inv) {
    const int n  = blockIdx.x * 64 + threadIdx.x;
    const int ks = blockIdx.y;
    if (ks == 0) zmask[n] = 0u;                 // fused clear
    int fid = (ks * 32 + blockIdx.x) * 64 + threadIdx.x;   // [0, 32768)
    if (fid < KN) inv[fid] = INVNONE;           // fused inv init
    const int k0 = ks * 32;
    double acc[16];
    #pragma unroll
    for (int b = 0; b < 16; ++b) acc[b] = 0.0;
    #pragma unroll 8
    for (int kk = 0; kk < 32; ++kk) {           // 8 W-loads batched in flight
        double w = (double)W[(size_t)(k0 + kk) * NN + n];   // coalesced 256B/wave
        #pragma unroll
        for (int b = 0; b < 16; ++b)                        // uniform scalar loads
            acc[b] += w * (double)inputs[b * NIN + k0 + kk];
    }
    #pragma unroll
    for (int b = 0; b < 16; ++b)
        part[(size_t)(ks * 16 + b) * NN + n] = acc[b];
}

// ---------------------------------------------------------------------------
// kM: inv[col] = min slot with ridx[slot]==col (atomicMin -> deterministic).
__global__ __launch_bounds__(256) void kM_min(const int* __restrict__ ridx,
                                              int* __restrict__ inv) {
    int i = blockIdx.x * 256 + threadIdx.x;     // [0, 2048)
    atomicMin(&inv[ridx[i]], i);
}

// ---------------------------------------------------------------------------
// k2: deterministic reduce of 16 partials + LIF update. Writes new_z, new_v,
// and per-neuron 16-bit spike mask (atomicOr = order-independent).
__global__ __launch_bounds__(256) void k2_point(const double* __restrict__ part,
                                                const float* __restrict__ old_v,
                                                const float* __restrict__ old_spike,
                                                const int* __restrict__ tt_p,
                                                float* __restrict__ out,      // z @0, v @32768
                                                unsigned int* __restrict__ zmask) {
    int gid = blockIdx.x * 256 + threadIdx.x;   // [0, 32768)
    int b = gid >> 11, n = gid & (NN - 1);
    double s = 0.0;
    #pragma unroll
    for (int ks = 0; ks < 16; ++ks)             // fixed order -> deterministic
        s += part[(size_t)(ks * 16 + b) * NN + n];
    double tt   = (double)tt_p[0];
    double bias = 0.5 * sin(2.0 * 3.14159265358979323846 * 4.0 * (0.001 * tt));
    double d    = 0.9512294245007140;           // exp(-1/20)
    double i_in = s + bias;
    double nv   = d * (double)old_v[gid] + (1.0 - d) * i_in
                  - 0.03 * (double)old_spike[gid];
    bool z = nv > 0.03;                          // v_scaled > 0  <=>  nv > THR
    out[gid]           = z ? 1.0f : 0.0f;
    out[32768 + gid]   = (float)nv;
    if (z) atomicOr(&zmask[n], 1u << b);
}

// ---------------------------------------------------------------------------
// k3: streamed masked row-sum of B (= new_z @ B).
// Inner loop unchanged (proven): float2/thread, UN=8 batched loads,
// branchless selector-FMA with wave-uniform mask.
// NEW: store only representative (needed) columns into compact[by][b][rep]
// (2 MB total instead of 29 MB) -> less HBM traffic + B stays L3-resident.
#define UN 8
__global__ __launch_bounds__(128) void k3_stream(const float2* __restrict__ B2,
                                                 const unsigned int* __restrict__ zmask,
                                                 const int* __restrict__ inv,
                                                 float* __restrict__ compact,
                                                 int nper) {
    __shared__ unsigned int smask[512];
    const int t    = threadIdx.x;
    const int col2 = blockIdx.x * 128 + t;       // [0, 14336)
    const int n0   = blockIdx.y * nper;
    for (int j = t; j < nper; j += 128) smask[j] = zmask[n0 + j];
    __syncthreads();

    float accx[16], accy[16];
    #pragma unroll
    for (int b = 0; b < 16; ++b) { accx[b] = 0.f; accy[b] = 0.f; }

    const float2* p = B2 + (size_t)n0 * KN2 + col2;
    for (int j = 0; j < nper; j += UN) {
        float2 v[UN];
        #pragma unroll
        for (int u = 0; u < UN; ++u)             // batched: 8 x 8B in flight
            v[u] = p[(size_t)(j + u) * KN2];
        #pragma unroll
        for (int u = 0; u < UN; ++u) {
            unsigned int m = (unsigned int)
                __builtin_amdgcn_readfirstlane((int)smask[j + u]);
            #pragma unroll
            for (int b = 0; b < 16; ++b) {
                float s = (m & (1u << b)) ? 1.0f : 0.0f;   // SGPR cselect
                accx[b] = fmaf(s, v[u].x, accx[b]);        // exact: +v or +0
                accy[b] = fmaf(s, v[u].y, accy[b]);
            }
        }
    }
    // Compact store: only columns that are some slot's representative.
    int r0 = inv[2 * col2];                      // even column
    int r1 = inv[2 * col2 + 1];                  // odd column
    float* cbase = compact + (size_t)blockIdx.y * 16 * 2048;
    if (r0 != INVNONE) {
        #pragma unroll
        for (int b = 0; b < 16; ++b) cbase[b * 2048 + r0] = accx[b];
    }
    if (r1 != INVNONE) {
        #pragma unroll
        for (int b = 0; b < 16; ++b) cbase[b * 2048 + r1] = accy[b];
    }
}

// ---------------------------------------------------------------------------
// k4: per output slot, sum NC chunk-partials of its representative column
// (fixed order). compact is 2 MB -> L2-hot.
__global__ __launch_bounds__(128) void k4_gather(const float* __restrict__ compact,
                                                 const int* __restrict__ ridx,
                                                 const int* __restrict__ inv,
                                                 float* __restrict__ out_z2,
                                                 int NC) {
    int gid = blockIdx.x * 128 + threadIdx.x;   // [0, 32768)
    int b = gid >> 11, i = gid & (NN - 1);
    int rep = inv[ridx[i]];                     // always valid (ridx[i] needed)
    float acc = 0.f;
    #pragma unroll 4
    for (int c = 0; c < NC; ++c)                // independent loads, pipelined
        acc += compact[(size_t)(c * 16 + b) * 2048 + rep];
    out_z2[gid] = acc;
}

// ---------------------------------------------------------------------------
extern "C" void kernel_launch(void* const* d_in, const int* in_sizes, int n_in,
                              void* d_out, int out_size, void* d_ws, size_t ws_size,
                              hipStream_t stream) {
    const float* inputs    = (const float*)d_in[0];
    const float* old_v     = (const float*)d_in[1];
    const float* old_spike = (const float*)d_in[2];
    const float* W         = (const float*)d_in[3];
    const float* Bw        = (const float*)d_in[4];
    const int*   ridx      = (const int*)d_in[5];
    const int*   tt        = (const int*)d_in[6];
    float* out = (float*)d_out;

    // ws layout: [0,4MB) f64 partials | 64KB zmask | 128KB inv | 2MB compact
    char* ws = (char*)d_ws;
    double*       part    = (double*)ws;
    unsigned int* zmask   = (unsigned int*)(ws + (4u << 20));
    int*          inv     = (int*)(ws + (4u << 20) + (64u << 10));
    float*        compact = (float*)(ws + (4u << 20) + (192u << 10));

    const int NC = 16;                           // n-chunks for k3
    const int nper = NN / NC;                    // 128, multiple of UN

    k1_gemm <<<dim3(32, 16), 64, 0, stream>>>(inputs, W, part, zmask, inv);
    kM_min  <<<8, 256, 0, stream>>>(ridx, inv);
    k2_point<<<128, 256, 0, stream>>>(part, old_v, old_spike, tt, out, zmask);
    k3_stream<<<dim3(112, NC), 128, 0, stream>>>((const float2*)Bw, zmask,
                                                 inv, compact, nper);
    k4_gather<<<256, 128, 0, stream>>>(compact, ridx, inv, out + 65536, NC);
}